// Round 2
// baseline (2198.206 us; speedup 1.0000x reference)
//
#include <hip/hip_runtime.h>
#include <stdint.h>
#include <math.h>

#define BB 4
#define NNODE 2048
#define NE 32768
#define DDIM 128
#define NL 3
#define NRELS 1000
#define MASKV -1000000000.0f

__device__ __forceinline__ float sigf(float x){ return 1.0f/(1.0f+expf(-x)); }

__device__ __forceinline__ float bf2f(unsigned short u){
  union { unsigned int i; float f; } v; v.i = ((unsigned int)u) << 16; return v.f;
}
__device__ __forceinline__ unsigned short f2bf(float x){
  union { float f; unsigned int u; } v; v.f = x;
  unsigned int r = (v.u + 0x7FFFu + ((v.u >> 16) & 1u)) >> 16;  // RNE
  return (unsigned short)r;
}

__device__ __forceinline__ void atomicMaxF(float* addr, float val){
  int cur = __float_as_int(*addr);
  while (__int_as_float(cur) < val){
    int assumed = cur;
    cur = atomicCAS((int*)addr, assumed, __float_as_int(val));
    if (cur == assumed) break;
  }
}

#define FMA4(acc, a, bv) do { \
    acc.x = fmaf(a, bv.x, acc.x); \
    acc.y = fmaf(a, bv.y, acc.y); \
    acc.z = fmaf(a, bv.z, acc.z); \
    acc.w = fmaf(a, bv.w, acc.w); } while(0)

// ------------------------------------------------------- mask dtype handling
// The harness's upload encoding for jnp bool arrays is unknown (uint8 / int32
// / float32 are all plausible). Probe the first 256 bytes (in-bounds under
// every interpretation) and classify; then decode both masks to clean uint8.
__global__ void probe_mask_kernel(const void* cm_raw, int* flag){
  int t = threadIdx.x;                       // 64 threads
  const int* ip = (const int*)cm_raw;
  unsigned v = (unsigned)ip[t];
  bool i32ok = (v <= 1u);
  bool f32ok = (v == 0u) || (v == 0x3F800000u);
  unsigned long long bi = __ballot(i32ok);
  unsigned long long bf_ = __ballot(f32ok);
  if (t == 0){
    int f;
    if (bi == ~0ULL) f = 0;          // int32 0/1
    else if (bf_ == ~0ULL) f = 1;    // float32 0.0/1.0
    else f = 2;                      // byte-wise bool
    *flag = f;
  }
}

__global__ void decode_masks_kernel(const void* cm_raw, const void* em_raw,
                                    const int* flag,
                                    uint8_t* __restrict__ cm, uint8_t* __restrict__ em){
  int i = blockIdx.x*256 + threadIdx.x;      // B*E threads
  int f = *flag;
  uint8_t c, e;
  if (f == 0){
    c = ((const int*)cm_raw)[i] != 0;  e = ((const int*)em_raw)[i] != 0;
  } else if (f == 1){
    c = ((const float*)cm_raw)[i] != 0.0f;  e = ((const float*)em_raw)[i] != 0.0f;
  } else {
    c = ((const uint8_t*)cm_raw)[i] != 0;  e = ((const uint8_t*)em_raw)[i] != 0;
  }
  cm[i] = c; em[i] = e;
}

// ---------------------------------------------------------------- init
__global__ void init_h_kernel(float* __restrict__ h){
  int gid = blockIdx.x*256 + threadIdx.x;          // B*N*D threads
  int nd = gid & (NNODE*DDIM - 1);
  h[gid] = (nd < DDIM) ? 1.0f : 0.0f;
}

__global__ void init_layer_kernel(float* __restrict__ aggr, float* __restrict__ mx, float* __restrict__ sm){
  int gid = blockIdx.x*256 + threadIdx.x;          // B*N*D threads
  aggr[gid] = 0.0f;
  if (gid < BB*NNODE){ mx[gid] = MASKV; sm[gid] = 0.0f; }
}

// ------------------------------------------------- per-rel / per-batch tables
__global__ void precomp_tables_kernel(
    const float* __restrict__ relt, const float* __restrict__ rq,
    const float* __restrict__ attW, const float* __restrict__ betaW,
    float* __restrict__ att_rel, float* __restrict__ att_rq,
    float* __restrict__ beta_rel, float* __restrict__ beta_rq)
{
  int wid = (blockIdx.x*256 + threadIdx.x) >> 6;
  int lane = threadIdx.x & 63;
  if (wid >= 3*NRELS + 3*BB + NRELS + BB) return;
  const float* vec; const float* w; float* dst; int di;
  if (wid < 3*NRELS){
    int k = wid/NRELS, rl = wid%NRELS;
    vec = relt + rl*DDIM; w = attW + k*384 + 128; dst = att_rel; di = wid;
  } else if (wid < 3*NRELS + 3*BB){
    int idx = wid - 3*NRELS; int k = idx/BB, b = idx%BB;
    vec = rq + b*DDIM; w = attW + k*384 + 256; dst = att_rq; di = idx;
  } else if (wid < 3*NRELS + 3*BB + NRELS){
    int rl = wid - (3*NRELS + 3*BB);
    vec = relt + rl*DDIM; w = betaW; dst = beta_rel; di = rl;
  } else {
    int b = wid - (3*NRELS + 3*BB + NRELS);
    vec = rq + b*DDIM; w = betaW; dst = beta_rq; di = b;
  }
  float s = vec[lane]*w[lane] + vec[lane+64]*w[lane+64];
  #pragma unroll
  for (int off=32; off; off>>=1) s += __shfl_xor(s, off, 64);
  if (lane == 0) dst[di] = s;
}

// ---------------------------------------------------- coef = gate*den*em
__global__ __launch_bounds__(256,2) void coef_kernel(
    const int* __restrict__ rels, const float* __restrict__ scores,
    const uint8_t* __restrict__ conf_mask, const uint8_t* __restrict__ edge_mask,
    const float* __restrict__ relt, const float* __restrict__ rq,
    const float* __restrict__ conf,
    const float* __restrict__ denW1, const float* __restrict__ denb1,
    const float* __restrict__ denW2, const float* __restrict__ denb2,
    const float* __restrict__ beta_rel, const float* __restrict__ beta_rq,
    const float* __restrict__ betab,
    float* __restrict__ coef)
{
  __shared__ float As[128*65];
  __shared__ float Bs[64*128];
  __shared__ int rel_s[128];
  const int t = threadIdx.x;
  const int blk = blockIdx.x;               // 1024 blocks
  const int b = blk >> 8;
  const int e0 = (blk & 255) << 7;
  const int ge0 = b*NE + e0;
  if (t < 128) rel_s[t] = rels[ge0 + t];

  const int c = t & 15, r = t >> 4;
  float4 acc0[8], acc1[8];
  #pragma unroll
  for (int i=0;i<8;++i){ acc0[i]=make_float4(0,0,0,0); acc1[i]=make_float4(0,0,0,0); }

  for (int ch=0; ch<6; ++ch){
    const int region = ch >> 1;
    const int d0 = (ch & 1) << 6;
    __syncthreads();
    if (region == 0){
      #pragma unroll
      for (int l=0;l<32;++l){
        int idx=(l<<8)+t, ei=idx>>6, kk=idx&63;
        As[ei*65+kk] = relt[rel_s[ei]*DDIM + d0 + kk];
      }
    } else if (region == 1){
      #pragma unroll
      for (int l=0;l<32;++l){
        int idx=(l<<8)+t, ei=idx>>6, kk=idx&63;
        As[ei*65+kk] = rq[b*DDIM + d0 + kk];
      }
    } else {
      #pragma unroll
      for (int l=0;l<32;++l){
        int idx=(l<<8)+t, ei=idx>>6, kk=idx&63;
        As[ei*65+kk] = conf[(size_t)(ge0+ei)*DDIM + d0 + kk];
      }
    }
    #pragma unroll
    for (int l=0;l<32;++l){
      int idx=(l<<8)+t, kk=idx>>7, j=idx&127;
      Bs[(kk<<7)+j] = denW1[(size_t)((ch<<6)+kk)*DDIM + j];
    }
    __syncthreads();
    #pragma unroll 4
    for (int kk=0;kk<64;++kk){
      const float4 b0 = *(const float4*)&Bs[(kk<<7) + (c<<2)];
      const float4 b1 = *(const float4*)&Bs[(kk<<7) + 64 + (c<<2)];
      #pragma unroll
      for (int i=0;i<8;++i){
        const float a = As[((r<<3)+i)*65 + kk];
        FMA4(acc0[i], a, b0);
        FMA4(acc1[i], a, b1);
      }
    }
  }

  const int col0 = c << 2;
  float db0[4], db1v[4], w20[4], w21[4];
  #pragma unroll
  for (int q=0;q<4;++q){
    db0[q] = denb1[col0+q];     db1v[q] = denb1[64+col0+q];
    w20[q] = denW2[col0+q];     w21[q]  = denW2[64+col0+q];
  }
  const float brq = beta_rq[b];
  const float bb0 = betab[0];
  const float db2 = denb2[0];

  #pragma unroll
  for (int i=0;i<8;++i){
    const int ei = (r<<3) + i;
    const int ge = ge0 + ei;
    float s;
    {
      float t0 = fmaxf(acc0[i].x + db0[0], 0.f) * w20[0];
      t0 = fmaf(fmaxf(acc0[i].y + db0[1], 0.f), w20[1], t0);
      t0 = fmaf(fmaxf(acc0[i].z + db0[2], 0.f), w20[2], t0);
      t0 = fmaf(fmaxf(acc0[i].w + db0[3], 0.f), w20[3], t0);
      t0 = fmaf(fmaxf(acc1[i].x + db1v[0], 0.f), w21[0], t0);
      t0 = fmaf(fmaxf(acc1[i].y + db1v[1], 0.f), w21[1], t0);
      t0 = fmaf(fmaxf(acc1[i].z + db1v[2], 0.f), w21[2], t0);
      t0 = fmaf(fmaxf(acc1[i].w + db1v[3], 0.f), w21[3], t0);
      s = t0;
    }
    #pragma unroll
    for (int off=1; off<16; off<<=1) s += __shfl_xor(s, off, 16);
    if (c == 0){
      float den_sig = sigf(s + db2);
      float em = edge_mask[ge] ? 1.0f : 0.0f;
      float beta = sigf(beta_rel[rel_s[ei]] + brq + bb0);
      float g = conf_mask[ge] ? sigf((scores[ge] - beta) * 10.0f) : 0.5f;
      coef[ge] = g * den_sig * em;
    }
  }
}

// ---------------------------------- msg GEMM + att + scatter-max (per layer)
__global__ __launch_bounds__(256,2) void msg_kernel(
    const int* __restrict__ edge_index, const int* __restrict__ rels,
    const uint8_t* __restrict__ edge_mask,
    const float* __restrict__ relt, const float* __restrict__ conf,
    const float* __restrict__ h,
    const float* __restrict__ msgW, const float* __restrict__ msgb,
    const float* __restrict__ attW, const float* __restrict__ attb,
    const float* __restrict__ att_rel, const float* __restrict__ att_rq,
    unsigned short* __restrict__ raw, float* __restrict__ att,
    float* __restrict__ mx, int layer)
{
  __shared__ float As[128*65];
  __shared__ float Bs[64*128];
  __shared__ int src_s[128];
  __shared__ int rel_s[128];
  const int t = threadIdx.x;
  const int blk = blockIdx.x;               // 1024 blocks
  const int b = blk >> 8;
  const int e0 = (blk & 255) << 7;
  const int ge0 = b*NE + e0;
  if (t < 128) src_s[t] = edge_index[(b<<16) + e0 + t];
  else rel_s[t-128] = rels[ge0 + t - 128];

  const int c = t & 15, r = t >> 4;
  float4 acc0[8], acc1[8];
  #pragma unroll
  for (int i=0;i<8;++i){ acc0[i]=make_float4(0,0,0,0); acc1[i]=make_float4(0,0,0,0); }

  const float* wbase = msgW + (size_t)layer*5*DDIM*DDIM;

  for (int ch=0; ch<10; ++ch){
    const int region = ch >> 1;
    const int d0 = (ch & 1) << 6;
    __syncthreads();
    if (region == 0){
      #pragma unroll
      for (int l=0;l<32;++l){
        int idx=(l<<8)+t, ei=idx>>6, kk=idx&63;
        As[ei*65+kk] = h[(size_t)((b<<11)+src_s[ei])*DDIM + d0 + kk]
                     * relt[rel_s[ei]*DDIM + d0 + kk];
      }
    } else if (region == 1){
      #pragma unroll
      for (int l=0;l<32;++l){
        int idx=(l<<8)+t, ei=idx>>6, kk=idx&63;
        As[ei*65+kk] = h[(size_t)((b<<11)+src_s[ei])*DDIM + d0 + kk];
      }
    } else if (region == 2){
      #pragma unroll
      for (int l=0;l<32;++l){
        int idx=(l<<8)+t, ei=idx>>6, kk=idx&63;
        As[ei*65+kk] = (src_s[ei]==0) ? 1.0f : 0.0f;
      }
    } else if (region == 3){
      #pragma unroll
      for (int l=0;l<32;++l){
        int idx=(l<<8)+t, ei=idx>>6, kk=idx&63;
        As[ei*65+kk] = relt[rel_s[ei]*DDIM + d0 + kk];
      }
    } else {
      #pragma unroll
      for (int l=0;l<32;++l){
        int idx=(l<<8)+t, ei=idx>>6, kk=idx&63;
        As[ei*65+kk] = conf[(size_t)(ge0+ei)*DDIM + d0 + kk];
      }
    }
    #pragma unroll
    for (int l=0;l<32;++l){
      int idx=(l<<8)+t, kk=idx>>7, j=idx&127;
      Bs[(kk<<7)+j] = wbase[(size_t)((ch<<6)+kk)*DDIM + j];
    }
    __syncthreads();
    #pragma unroll 4
    for (int kk=0;kk<64;++kk){
      const float4 b0 = *(const float4*)&Bs[(kk<<7) + (c<<2)];
      const float4 b1 = *(const float4*)&Bs[(kk<<7) + 64 + (c<<2)];
      #pragma unroll
      for (int i=0;i<8;++i){
        const float a = As[((r<<3)+i)*65 + kk];
        FMA4(acc0[i], a, b0);
        FMA4(acc1[i], a, b1);
      }
    }
  }

  const int col0 = c << 2;
  const float* mb = msgb + layer*DDIM;
  const float* aw = attW + layer*3*DDIM;
  float mb0[4], mb1[4], aw0[4], aw1[4];
  #pragma unroll
  for (int q=0;q<4;++q){
    mb0[q] = mb[col0+q];    mb1[q] = mb[64+col0+q];
    aw0[q] = aw[col0+q];    aw1[q] = aw[64+col0+q];
  }
  const float arq = att_rq[layer*BB + b];
  const float ab  = attb[layer];

  #pragma unroll
  for (int i=0;i<8;++i){
    const int ei = (r<<3) + i;
    const int ge = ge0 + ei;
    float4 r0, r1;
    r0.x = fmaxf(acc0[i].x + mb0[0], 0.f);
    r0.y = fmaxf(acc0[i].y + mb0[1], 0.f);
    r0.z = fmaxf(acc0[i].z + mb0[2], 0.f);
    r0.w = fmaxf(acc0[i].w + mb0[3], 0.f);
    r1.x = fmaxf(acc1[i].x + mb1[0], 0.f);
    r1.y = fmaxf(acc1[i].y + mb1[1], 0.f);
    r1.z = fmaxf(acc1[i].z + mb1[2], 0.f);
    r1.w = fmaxf(acc1[i].w + mb1[3], 0.f);
    float p = r0.x*aw0[0] + r0.y*aw0[1] + r0.z*aw0[2] + r0.w*aw0[3]
            + r1.x*aw1[0] + r1.y*aw1[1] + r1.z*aw1[2] + r1.w*aw1[3];
    ushort4 s0, s1;
    s0.x=f2bf(r0.x); s0.y=f2bf(r0.y); s0.z=f2bf(r0.z); s0.w=f2bf(r0.w);
    s1.x=f2bf(r1.x); s1.y=f2bf(r1.y); s1.z=f2bf(r1.z); s1.w=f2bf(r1.w);
    *(ushort4*)&raw[(size_t)ge*DDIM + col0] = s0;
    *(ushort4*)&raw[(size_t)ge*DDIM + 64 + col0] = s1;
    #pragma unroll
    for (int off=1; off<16; off<<=1) p += __shfl_xor(p, off, 16);
    if (c == 0){
      float a = p + att_rel[layer*NRELS + rel_s[ei]] + arq + ab;
      a = (a >= 0.f) ? a : 0.01f*a;
      const bool m = edge_mask[ge] != 0;
      a = m ? a : MASKV;
      att[ge] = a;
      if (m){
        const int tgt = edge_index[(b<<16) + NE + e0 + ei];
        atomicMaxF(&mx[(b<<11) + tgt], a);
      }
    }
  }
}

// -------------------------------------------------- softmax pass 2: ex & sum
__global__ void softmax_e_kernel(const int* __restrict__ edge_index,
                                 float* __restrict__ att_ex,
                                 const float* __restrict__ mx,
                                 float* __restrict__ sm)
{
  int gid = blockIdx.x*256 + threadIdx.x;   // B*E threads
  int b = gid >> 15;
  int e = gid & (NE-1);
  int tgt = edge_index[(b<<16) + NE + e];
  float a = att_ex[gid];
  float ex = expf(a - mx[(b<<11) + tgt]);
  att_ex[gid] = ex;
  atomicAdd(&sm[(b<<11) + tgt], ex);
}

// ------------------------------------------- weighted scatter-add of messages
__global__ void aggregate_kernel(const int* __restrict__ edge_index,
                                 const float* __restrict__ att_ex,
                                 const float* __restrict__ sm,
                                 const float* __restrict__ coef,
                                 const unsigned short* __restrict__ raw,
                                 float* __restrict__ aggr)
{
  int gid = blockIdx.x*256 + threadIdx.x;   // B*E*D threads
  int ge = gid >> 7;
  int d = gid & 127;
  float cf = coef[ge];
  if (cf == 0.0f) return;
  int b = ge >> 15;
  int e = ge & (NE-1);
  int tgt = edge_index[(b<<16) + NE + e];
  float alpha = att_ex[ge] / (sm[(b<<11) + tgt] + 1e-8f);
  float w = cf * alpha;
  atomicAdd(&aggr[(size_t)((b<<11) + tgt)*DDIM + d], w * bf2f(raw[(size_t)ge*DDIM + d]));
}

// --------------------------------------------- h = LN(h + aggr@updW + updb)
__global__ __launch_bounds__(256,2) void update_kernel(
    const float* __restrict__ aggr, const float* __restrict__ updW,
    const float* __restrict__ updb,
    const float* __restrict__ lng, const float* __restrict__ lnb,
    float* __restrict__ h, float* __restrict__ out, int layer)
{
  __shared__ float As[64*65];
  __shared__ float Bs[64*128];
  const int t = threadIdx.x, blk = blockIdx.x;   // 128 blocks
  const int n0 = blk << 6;
  const int c = t & 15, r = t >> 4;
  float4 acc0[4], acc1[4];
  #pragma unroll
  for (int i=0;i<4;++i){ acc0[i]=make_float4(0,0,0,0); acc1[i]=make_float4(0,0,0,0); }
  const float* wbase = updW + (size_t)layer*DDIM*DDIM;

  for (int ch=0; ch<2; ++ch){
    __syncthreads();
    #pragma unroll
    for (int l=0;l<16;++l){
      int idx=(l<<8)+t, ei=idx>>6, kk=idx&63;
      As[ei*65+kk] = aggr[(size_t)(n0+ei)*DDIM + (ch<<6) + kk];
    }
    #pragma unroll
    for (int l=0;l<32;++l){
      int idx=(l<<8)+t, kk=idx>>7, j=idx&127;
      Bs[(kk<<7)+j] = wbase[((ch<<6)+kk)*DDIM + j];
    }
    __syncthreads();
    #pragma unroll 4
    for (int kk=0;kk<64;++kk){
      const float4 b0 = *(const float4*)&Bs[(kk<<7) + (c<<2)];
      const float4 b1 = *(const float4*)&Bs[(kk<<7) + 64 + (c<<2)];
      #pragma unroll
      for (int i=0;i<4;++i){
        const float a = As[((r<<2)+i)*65 + kk];
        FMA4(acc0[i], a, b0);
        FMA4(acc1[i], a, b1);
      }
    }
  }

  const int col0 = c << 2;
  float ub0[4], ub1[4], g0[4], g1[4], lb0[4], lb1[4];
  #pragma unroll
  for (int q=0;q<4;++q){
    ub0[q] = updb[layer*DDIM + col0+q];  ub1[q] = updb[layer*DDIM + 64+col0+q];
    g0[q]  = lng[col0+q];                g1[q]  = lng[64+col0+q];
    lb0[q] = lnb[col0+q];                lb1[q] = lnb[64+col0+q];
  }

  #pragma unroll
  for (int i=0;i<4;++i){
    const int row = n0 + (r<<2) + i;
    float* hrow = h + (size_t)row*DDIM;
    float4 h0 = *(float4*)&hrow[col0];
    float4 h1 = *(float4*)&hrow[64+col0];
    float x0[4], x1[4];
    x0[0] = h0.x + acc0[i].x + ub0[0];
    x0[1] = h0.y + acc0[i].y + ub0[1];
    x0[2] = h0.z + acc0[i].z + ub0[2];
    x0[3] = h0.w + acc0[i].w + ub0[3];
    x1[0] = h1.x + acc1[i].x + ub1[0];
    x1[1] = h1.y + acc1[i].y + ub1[1];
    x1[2] = h1.z + acc1[i].z + ub1[2];
    x1[3] = h1.w + acc1[i].w + ub1[3];
    float s = 0.f, s2 = 0.f;
    #pragma unroll
    for (int q=0;q<4;++q){ s += x0[q]+x1[q]; s2 += x0[q]*x0[q] + x1[q]*x1[q]; }
    #pragma unroll
    for (int off=1; off<16; off<<=1){
      s  += __shfl_xor(s,  off, 16);
      s2 += __shfl_xor(s2, off, 16);
    }
    const float mu = s * (1.0f/128.0f);
    const float var = s2 * (1.0f/128.0f) - mu*mu;
    const float rstd = rsqrtf(var + 1e-5f);
    float4 y0, y1;
    y0.x = (x0[0]-mu)*rstd*g0[0] + lb0[0];
    y0.y = (x0[1]-mu)*rstd*g0[1] + lb0[1];
    y0.z = (x0[2]-mu)*rstd*g0[2] + lb0[2];
    y0.w = (x0[3]-mu)*rstd*g0[3] + lb0[3];
    y1.x = (x1[0]-mu)*rstd*g1[0] + lb1[0];
    y1.y = (x1[1]-mu)*rstd*g1[1] + lb1[1];
    y1.z = (x1[2]-mu)*rstd*g1[2] + lb1[2];
    y1.w = (x1[3]-mu)*rstd*g1[3] + lb1[3];
    *(float4*)&hrow[col0] = y0;
    *(float4*)&hrow[64+col0] = y1;
    if ((row & (NNODE-1)) == 0){
      const int bb_ = row >> 11;
      float* op = out + (size_t)(bb_*NL + layer)*DDIM;
      *(float4*)&op[col0] = y0;
      *(float4*)&op[64+col0] = y1;
    }
  }
}

// ------------------------------------------------------------------ launcher
extern "C" void kernel_launch(void* const* d_in, const int* in_sizes, int n_in,
                              void* d_out, int out_size, void* d_ws, size_t ws_size,
                              hipStream_t stream) {
  const int*   edge_index = (const int*)d_in[0];
  const int*   rels       = (const int*)d_in[1];
  const float* scores     = (const float*)d_in[2];
  const void*  cm_raw     = d_in[3];
  const void*  em_raw     = d_in[4];
  // d_in[5] = mask (unused: all ones, only shape matters)
  const float* rq    = (const float*)d_in[6];
  const float* conf  = (const float*)d_in[7];
  const float* relt  = (const float*)d_in[8];
  const float* betaW = (const float*)d_in[9];
  const float* betab = (const float*)d_in[10];
  const float* msgW  = (const float*)d_in[11];
  const float* msgb  = (const float*)d_in[12];
  const float* updW  = (const float*)d_in[13];
  const float* updb  = (const float*)d_in[14];
  const float* lng   = (const float*)d_in[15];
  const float* lnb   = (const float*)d_in[16];
  const float* attW  = (const float*)d_in[17];
  const float* attb  = (const float*)d_in[18];
  const float* denW1 = (const float*)d_in[19];
  const float* denb1 = (const float*)d_in[20];
  const float* denW2 = (const float*)d_in[21];
  const float* denb2 = (const float*)d_in[22];
  float* out = (float*)d_out;
  char* ws = (char*)d_ws;

  size_t off = 0;
  float* h        = (float*)(ws + off); off += (size_t)BB*NNODE*DDIM*4;     //  4 MB
  float* aggr     = (float*)(ws + off); off += (size_t)BB*NNODE*DDIM*4;     //  4 MB
  unsigned short* raw = (unsigned short*)(ws + off); off += (size_t)BB*NE*DDIM*2; // 32 MB
  float* coef     = (float*)(ws + off); off += (size_t)BB*NE*4;             // 512 KB
  float* att      = (float*)(ws + off); off += (size_t)BB*NE*4;             // 512 KB
  float* mx       = (float*)(ws + off); off += (size_t)BB*NNODE*4;          //  32 KB
  float* sm       = (float*)(ws + off); off += (size_t)BB*NNODE*4;          //  32 KB
  float* att_rel  = (float*)(ws + off); off += 3*NRELS*4 + 32;
  float* att_rq   = (float*)(ws + off); off += 64;
  float* beta_rel = (float*)(ws + off); off += NRELS*4 + 32;
  float* beta_rq  = (float*)(ws + off); off += 64;
  uint8_t* cm_dec = (uint8_t*)(ws + off); off += (size_t)BB*NE;
  uint8_t* em_dec = (uint8_t*)(ws + off); off += (size_t)BB*NE;
  int* flag       = (int*)(ws + off); off += 64;

  probe_mask_kernel<<<1, 64, 0, stream>>>(cm_raw, flag);
  decode_masks_kernel<<<512, 256, 0, stream>>>(cm_raw, em_raw, flag, cm_dec, em_dec);
  init_h_kernel<<<4096, 256, 0, stream>>>(h);
  precomp_tables_kernel<<<1004, 256, 0, stream>>>(relt, rq, attW, betaW,
                                                  att_rel, att_rq, beta_rel, beta_rq);
  coef_kernel<<<1024, 256, 0, stream>>>(rels, scores, cm_dec, em_dec,
                                        relt, rq, conf, denW1, denb1, denW2, denb2,
                                        beta_rel, beta_rq, betab, coef);
  for (int k = 0; k < NL; ++k){
    init_layer_kernel<<<4096, 256, 0, stream>>>(aggr, mx, sm);
    msg_kernel<<<1024, 256, 0, stream>>>(edge_index, rels, em_dec, relt, conf, h,
                                         msgW, msgb, attW, attb, att_rel, att_rq,
                                         raw, att, mx, k);
    softmax_e_kernel<<<512, 256, 0, stream>>>(edge_index, att, mx, sm);
    aggregate_kernel<<<65536, 256, 0, stream>>>(edge_index, att, sm, coef, raw, aggr);
    update_kernel<<<128, 256, 0, stream>>>(aggr, updW, updb, lng, lnb, h, out, k);
  }
}

// Round 3
// 565.949 us; speedup vs baseline: 3.8841x; 3.8841x over previous
//
#include <hip/hip_runtime.h>
#include <stdint.h>
#include <math.h>

#define BB 4
#define NNODE 2048
#define NE 32768
#define DDIM 128
#define NL 3
#define NRELS 1000
#define MASKV -1000000000.0f

typedef unsigned short ushort_t;
typedef __attribute__((ext_vector_type(8))) short bfrag;   // 8 bf16 (4 VGPR)
typedef __attribute__((ext_vector_type(4))) float f4;

__device__ __forceinline__ float sigf(float x){ return 1.0f/(1.0f+expf(-x)); }

__device__ __forceinline__ float bf2f(ushort_t u){
  union { unsigned int i; float f; } v; v.i = ((unsigned int)u) << 16; return v.f;
}
__device__ __forceinline__ ushort_t f2bf(float x){
  union { float f; unsigned int u; } v; v.f = x;
  unsigned int r = (v.u + 0x7FFFu + ((v.u >> 16) & 1u)) >> 16;  // RNE
  return (ushort_t)r;
}
__device__ __forceinline__ float bflo(unsigned u){
  union{unsigned i;float f;}v; v.i=u<<16; return v.f;
}
__device__ __forceinline__ float bfhi(unsigned u){
  union{unsigned i;float f;}v; v.i=u&0xFFFF0000u; return v.f;
}
__device__ __forceinline__ unsigned pmul_bf(unsigned a, unsigned b){
  return (unsigned)f2bf(bflo(a)*bflo(b)) | ((unsigned)f2bf(bfhi(a)*bfhi(b))<<16);
}

__device__ __forceinline__ void atomicMaxF(float* addr, float val){
  int cur = __float_as_int(*addr);
  while (__int_as_float(cur) < val){
    int assumed = cur;
    cur = atomicCAS((int*)addr, assumed, __float_as_int(val));
    if (cur == assumed) break;
  }
}

// ------------------------------------------------------- mask dtype handling
__global__ void probe_mask_kernel(const void* cm_raw, int* flag){
  int t = threadIdx.x;                       // 64 threads
  const int* ip = (const int*)cm_raw;
  unsigned v = (unsigned)ip[t];
  bool i32ok = (v <= 1u);
  bool f32ok = (v == 0u) || (v == 0x3F800000u);
  unsigned long long bi = __ballot(i32ok);
  unsigned long long bf_ = __ballot(f32ok);
  if (t == 0){
    int f;
    if (bi == ~0ULL) f = 0;
    else if (bf_ == ~0ULL) f = 1;
    else f = 2;
    *flag = f;
  }
}

__global__ void decode_masks_kernel(const void* cm_raw, const void* em_raw,
                                    const int* flag,
                                    uint8_t* __restrict__ cm, uint8_t* __restrict__ em){
  int i = blockIdx.x*256 + threadIdx.x;      // B*E threads
  int f = *flag;
  uint8_t c, e;
  if (f == 0){
    c = ((const int*)cm_raw)[i] != 0;  e = ((const int*)em_raw)[i] != 0;
  } else if (f == 1){
    c = ((const float*)cm_raw)[i] != 0.0f;  e = ((const float*)em_raw)[i] != 0.0f;
  } else {
    c = ((const uint8_t*)cm_raw)[i] != 0;  e = ((const uint8_t*)em_raw)[i] != 0;
  }
  cm[i] = c; em[i] = e;
}

// ---------------------------------------------------------------- converts
__global__ void conv_bf16_kernel(const float* __restrict__ src,
                                 ushort_t* __restrict__ dst, int n4){
  int gid = blockIdx.x*256 + threadIdx.x;
  if (gid >= n4) return;
  float4 v = *(const float4*)&src[(size_t)gid*4];
  ushort4 o;
  o.x=f2bf(v.x); o.y=f2bf(v.y); o.z=f2bf(v.z); o.w=f2bf(v.w);
  *(ushort4*)&dst[(size_t)gid*4] = o;
}

// Weight LDS-images: transposed, bf16, chunk-contiguous, XOR-swizzled so the
// staging path is a pure linear copy. Image elem e of chunk: j=e>>6 (col),
// kkb = ((e&63)<<1) ^ ((j&7)<<4), kk = kkb>>1 (k within chunk).
__global__ void build_wimg_kernel(const float* __restrict__ msgW,
                                  const float* __restrict__ denW1,
                                  ushort_t* __restrict__ img_msg,
                                  ushort_t* __restrict__ img_den){
  int e = blockIdx.x*256 + threadIdx.x;      // 36*8192 = 294912 threads
  int img_id = e >> 13;
  int ei = e & 8191;
  int j = ei >> 6;
  int kkb = ((ei & 63) << 1) ^ ((j & 7) << 4);
  int kk = kkb >> 1;
  if (img_id < 30){
    int layer = img_id / 10, ch = img_id % 10;
    float v = msgW[((size_t)layer*640 + ch*64 + kk)*128 + j];
    img_msg[(size_t)img_id*8192 + ei] = f2bf(v);
  } else {
    int ch = img_id - 30;
    float v = denW1[((size_t)ch*64 + kk)*128 + j];
    img_den[(size_t)ch*8192 + ei] = f2bf(v);
  }
}

// ---------------------------------------------------------------- init
__global__ void init_h_kernel(float* __restrict__ h, ushort_t* __restrict__ h_bf){
  int gid = blockIdx.x*256 + threadIdx.x;          // B*N*D threads
  int nd = gid & (NNODE*DDIM - 1);
  bool one = (nd < DDIM);
  h[gid] = one ? 1.0f : 0.0f;
  h_bf[gid] = one ? 0x3F80 : 0;
}

__global__ void init_layer_kernel(float* __restrict__ aggr, float* __restrict__ mx, float* __restrict__ sm){
  int gid = blockIdx.x*256 + threadIdx.x;          // B*N*D threads
  aggr[gid] = 0.0f;
  if (gid < BB*NNODE){ mx[gid] = MASKV; sm[gid] = 0.0f; }
}

// ------------------------------------------------- per-rel / per-batch tables
__global__ void precomp_tables_kernel(
    const float* __restrict__ relt, const float* __restrict__ rq,
    const float* __restrict__ attW, const float* __restrict__ betaW,
    float* __restrict__ att_rel, float* __restrict__ att_rq,
    float* __restrict__ beta_rel, float* __restrict__ beta_rq)
{
  int wid = (blockIdx.x*256 + threadIdx.x) >> 6;
  int lane = threadIdx.x & 63;
  if (wid >= 3*NRELS + 3*BB + NRELS + BB) return;
  const float* vec; const float* w; float* dst; int di;
  if (wid < 3*NRELS){
    int k = wid/NRELS, rl = wid%NRELS;
    vec = relt + rl*DDIM; w = attW + k*384 + 128; dst = att_rel; di = wid;
  } else if (wid < 3*NRELS + 3*BB){
    int idx = wid - 3*NRELS; int k = idx/BB, b = idx%BB;
    vec = rq + b*DDIM; w = attW + k*384 + 256; dst = att_rq; di = idx;
  } else if (wid < 3*NRELS + 3*BB + NRELS){
    int rl = wid - (3*NRELS + 3*BB);
    vec = relt + rl*DDIM; w = betaW; dst = beta_rel; di = rl;
  } else {
    int b = wid - (3*NRELS + 3*BB + NRELS);
    vec = rq + b*DDIM; w = betaW; dst = beta_rq; di = b;
  }
  float s = vec[lane]*w[lane] + vec[lane+64]*w[lane+64];
  #pragma unroll
  for (int off=32; off; off>>=1) s += __shfl_xor(s, off, 64);
  if (lane == 0) dst[di] = s;
}

// ================================================= MFMA coef kernel
// GEMM (B*E,384)@(384,128): A = [h_r | rq | conf] in bf16, den-head epilogue.
__global__ __launch_bounds__(256,2) void coef_mfma_kernel(
    const int* __restrict__ rels, const float* __restrict__ scores,
    const uint8_t* __restrict__ cm, const uint8_t* __restrict__ em,
    const ushort_t* __restrict__ relt_bf, const ushort_t* __restrict__ rq_bf,
    const ushort_t* __restrict__ conf_bf, const ushort_t* __restrict__ img_den,
    const float* __restrict__ denb1, const float* __restrict__ denW2,
    const float* __restrict__ denb2,
    const float* __restrict__ beta_rel, const float* __restrict__ beta_rq,
    const float* __restrict__ betab,
    float* __restrict__ coef)
{
  __shared__ char lds[32768];          // As[0,16K) Bs[16K,32K)
  __shared__ float att_buf[2][128];
  __shared__ int rel_s[128];

  const int t = threadIdx.x;
  const int blk = blockIdx.x;               // 1024 blocks
  const int b = blk >> 8;
  const int e0 = (blk & 255) << 7;
  const int ge0 = b*NE + e0;
  if (t < 128) rel_s[t] = rels[ge0 + t];

  const int lane = t & 63, wid = t >> 6;
  const int wr = wid >> 1, wc = wid & 1;
  const int rbase = wr << 6, cbase = wc << 6;
  const int lr = lane & 15, lk = lane >> 4;
  const int swz = (lane & 7) << 4;

  f4 acc[4][4];
  #pragma unroll
  for (int m=0;m<4;++m)
    #pragma unroll
    for (int n=0;n<4;++n)
      acc[m][n] = (f4){0.f,0.f,0.f,0.f};

  const uint4* imgp = (const uint4*)img_den;

  __syncthreads();   // rel_s ready

  for (int ch=0; ch<6; ++ch){
    const int region = ch >> 1, d0 = (ch & 1) << 6;
    uint4 br0 = imgp[ch*1024 + t];
    uint4 br1 = imgp[ch*1024 + 256 + t];
    uint4 br2 = imgp[ch*1024 + 512 + t];
    uint4 br3 = imgp[ch*1024 + 768 + t];
    #pragma unroll
    for (int i=0;i<4;++i){
      int u = t + (i<<8);
      int row = u >> 3, g = u & 7;
      char* dst = lds + row*128 + ((g<<4) ^ ((row&7)<<4));
      uint4 val;
      if (region == 0){
        val = *(const uint4*)&relt_bf[(((size_t)rel_s[row])<<7) + d0 + (g<<3)];
      } else if (region == 1){
        val = *(const uint4*)&rq_bf[(b<<7) + d0 + (g<<3)];
      } else {
        val = *(const uint4*)&conf_bf[(((size_t)(ge0+row))<<7) + d0 + (g<<3)];
      }
      *(uint4*)dst = val;
    }
    *(uint4*)(lds + 16384 + (t<<4))         = br0;
    *(uint4*)(lds + 16384 + (t<<4) + 4096)  = br1;
    *(uint4*)(lds + 16384 + (t<<4) + 8192)  = br2;
    *(uint4*)(lds + 16384 + (t<<4) + 12288) = br3;
    __syncthreads();
    #pragma unroll
    for (int s=0;s<2;++s){
      bfrag af[4], bfr[4];
      #pragma unroll
      for (int m=0;m<4;++m)
        af[m] = *(const bfrag*)(lds + (rbase+(m<<4)+lr)*128 + (((s<<6)+(lk<<4)) ^ swz));
      #pragma unroll
      for (int n=0;n<4;++n)
        bfr[n] = *(const bfrag*)(lds + 16384 + (cbase+(n<<4)+lr)*128 + (((s<<6)+(lk<<4)) ^ swz));
      #pragma unroll
      for (int m=0;m<4;++m)
        #pragma unroll
        for (int n=0;n<4;++n)
          acc[m][n] = __builtin_amdgcn_mfma_f32_16x16x32_bf16(af[m], bfr[n], acc[m][n], 0,0,0);
    }
    __syncthreads();
  }

  float b1v[4], w2[4];
  #pragma unroll
  for (int n=0;n<4;++n){
    int col = cbase + (n<<4) + lr;
    b1v[n] = denb1[col]; w2[n] = denW2[col];
  }
  float p[4][4];
  #pragma unroll
  for (int m=0;m<4;++m)
    #pragma unroll
    for (int q=0;q<4;++q) p[m][q] = 0.f;
  #pragma unroll
  for (int m=0;m<4;++m)
    #pragma unroll
    for (int n=0;n<4;++n)
      #pragma unroll
      for (int q=0;q<4;++q){
        float v = fmaxf(acc[m][n][q] + b1v[n], 0.f);
        p[m][q] = fmaf(v, w2[n], p[m][q]);
      }
  #pragma unroll
  for (int m=0;m<4;++m)
    #pragma unroll
    for (int q=0;q<4;++q){
      #pragma unroll
      for (int off=1; off<16; off<<=1) p[m][q] += __shfl_xor(p[m][q], off, 64);
    }
  if (lr == 0){
    #pragma unroll
    for (int m=0;m<4;++m)
      #pragma unroll
      for (int q=0;q<4;++q)
        att_buf[wc][rbase + (m<<4) + (lk<<2) + q] = p[m][q];
  }
  __syncthreads();
  if (t < 128){
    int ge = ge0 + t;
    float s = att_buf[0][t] + att_buf[1][t];
    float den = sigf(s + denb2[0]);
    float emv = em[ge] ? 1.0f : 0.0f;
    float beta = sigf(beta_rel[rel_s[t]] + beta_rq[b] + betab[0]);
    float g = cm[ge] ? sigf((scores[ge]-beta)*10.0f) : 0.5f;
    coef[ge] = g * den * emv;
  }
}

// ================================================= MFMA msg kernel
// GEMM (B*E,640)@(640,128): A = [h*h_r | h | 1[src=0] | h_r | conf] bf16.
// Epilogue: relu+bias, att row-dot, raw tile -> LDS transpose -> coalesced
// bf16 stores, att scatter-max.
__global__ __launch_bounds__(256,2) void msg_mfma_kernel(
    const int* __restrict__ edge_index, const int* __restrict__ rels,
    const uint8_t* __restrict__ em,
    const ushort_t* __restrict__ relt_bf, const ushort_t* __restrict__ conf_bf,
    const ushort_t* __restrict__ h_bf, const ushort_t* __restrict__ img_msg,
    const float* __restrict__ msgb,
    const float* __restrict__ attW, const float* __restrict__ attb,
    const float* __restrict__ att_rel, const float* __restrict__ att_rq,
    ushort_t* __restrict__ raw, float* __restrict__ att,
    float* __restrict__ mx, int layer)
{
  __shared__ char lds[32768];          // stage: As[0,16K) Bs[16K,32K); epi: raw[0,32K)
  __shared__ float att_buf[2][128];
  __shared__ int src_s[128];
  __shared__ int rel_s[128];

  const int t = threadIdx.x;
  const int blk = blockIdx.x;               // 1024 blocks
  const int b = blk >> 8;
  const int e0 = (blk & 255) << 7;
  const int ge0 = b*NE + e0;
  if (t < 128) src_s[t] = edge_index[(b<<16) + e0 + t];
  else rel_s[t-128] = rels[ge0 + t - 128];

  const int lane = t & 63, wid = t >> 6;
  const int wr = wid >> 1, wc = wid & 1;
  const int rbase = wr << 6, cbase = wc << 6;
  const int lr = lane & 15, lk = lane >> 4;
  const int swz = (lane & 7) << 4;

  f4 acc[4][4];
  #pragma unroll
  for (int m=0;m<4;++m)
    #pragma unroll
    for (int n=0;n<4;++n)
      acc[m][n] = (f4){0.f,0.f,0.f,0.f};

  const uint4* imgp = (const uint4*)(img_msg + (size_t)layer*10*8192);

  __syncthreads();   // src_s/rel_s ready

  for (int ch=0; ch<10; ++ch){
    const int region = ch >> 1, d0 = (ch & 1) << 6;
    uint4 br0 = imgp[ch*1024 + t];
    uint4 br1 = imgp[ch*1024 + 256 + t];
    uint4 br2 = imgp[ch*1024 + 512 + t];
    uint4 br3 = imgp[ch*1024 + 768 + t];
    #pragma unroll
    for (int i=0;i<4;++i){
      int u = t + (i<<8);
      int row = u >> 3, g = u & 7;
      char* dst = lds + row*128 + ((g<<4) ^ ((row&7)<<4));
      uint4 val;
      if (region == 0){
        uint4 hv = *(const uint4*)&h_bf[(((size_t)(b<<11) + src_s[row])<<7) + d0 + (g<<3)];
        uint4 rv = *(const uint4*)&relt_bf[(((size_t)rel_s[row])<<7) + d0 + (g<<3)];
        val.x = pmul_bf(hv.x, rv.x); val.y = pmul_bf(hv.y, rv.y);
        val.z = pmul_bf(hv.z, rv.z); val.w = pmul_bf(hv.w, rv.w);
      } else if (region == 1){
        val = *(const uint4*)&h_bf[(((size_t)(b<<11) + src_s[row])<<7) + d0 + (g<<3)];
      } else if (region == 2){
        unsigned o = (src_s[row]==0) ? 0x3F803F80u : 0u;
        val.x=o; val.y=o; val.z=o; val.w=o;
      } else if (region == 3){
        val = *(const uint4*)&relt_bf[(((size_t)rel_s[row])<<7) + d0 + (g<<3)];
      } else {
        val = *(const uint4*)&conf_bf[(((size_t)(ge0+row))<<7) + d0 + (g<<3)];
      }
      *(uint4*)dst = val;
    }
    *(uint4*)(lds + 16384 + (t<<4))         = br0;
    *(uint4*)(lds + 16384 + (t<<4) + 4096)  = br1;
    *(uint4*)(lds + 16384 + (t<<4) + 8192)  = br2;
    *(uint4*)(lds + 16384 + (t<<4) + 12288) = br3;
    __syncthreads();
    #pragma unroll
    for (int s=0;s<2;++s){
      bfrag af[4], bfr[4];
      #pragma unroll
      for (int m=0;m<4;++m)
        af[m] = *(const bfrag*)(lds + (rbase+(m<<4)+lr)*128 + (((s<<6)+(lk<<4)) ^ swz));
      #pragma unroll
      for (int n=0;n<4;++n)
        bfr[n] = *(const bfrag*)(lds + 16384 + (cbase+(n<<4)+lr)*128 + (((s<<6)+(lk<<4)) ^ swz));
      #pragma unroll
      for (int m=0;m<4;++m)
        #pragma unroll
        for (int n=0;n<4;++n)
          acc[m][n] = __builtin_amdgcn_mfma_f32_16x16x32_bf16(af[m], bfr[n], acc[m][n], 0,0,0);
    }
    __syncthreads();
  }

  // ---- epilogue: relu+bias, att partials, raw->LDS (swizzled transpose)
  float bias[4], aw[4];
  #pragma unroll
  for (int n=0;n<4;++n){
    int col = cbase + (n<<4) + lr;
    bias[n] = msgb[layer*DDIM + col];
    aw[n]   = attW[layer*3*DDIM + col];
  }
  float p[4][4];
  #pragma unroll
  for (int m=0;m<4;++m)
    #pragma unroll
    for (int q=0;q<4;++q) p[m][q] = 0.f;
  #pragma unroll
  for (int m=0;m<4;++m)
    #pragma unroll
    for (int n=0;n<4;++n)
      #pragma unroll
      for (int q=0;q<4;++q){
        float v = fmaxf(acc[m][n][q] + bias[n], 0.f);
        p[m][q] = fmaf(v, aw[n], p[m][q]);
        int row = rbase + (m<<4) + (lk<<2) + q;
        int col = cbase + (n<<4) + lr;
        *(ushort_t*)(lds + (row<<8) + ((col<<1) ^ ((row&7)<<4))) = f2bf(v);
      }
  #pragma unroll
  for (int m=0;m<4;++m)
    #pragma unroll
    for (int q=0;q<4;++q){
      #pragma unroll
      for (int off=1; off<16; off<<=1) p[m][q] += __shfl_xor(p[m][q], off, 64);
    }
  if (lr == 0){
    #pragma unroll
    for (int m=0;m<4;++m)
      #pragma unroll
      for (int q=0;q<4;++q)
        att_buf[wc][rbase + (m<<4) + (lk<<2) + q] = p[m][q];
  }
  __syncthreads();

  // coalesced raw writeout (un-swizzle: 16B groups within a 256B row)
  #pragma unroll
  for (int i=0;i<8;++i){
    int u = t + (i<<8);                 // 2048 units of 16B
    int row = u >> 4, g = u & 15;
    uint4 v = *(const uint4*)(lds + (row<<8) + ((g<<4) ^ ((row&7)<<4)));
    *(uint4*)&raw[(((size_t)(ge0+row))<<7) + (g<<3)] = v;
  }
  // att finalize + scatter-max
  if (t < 128){
    int ge = ge0 + t;
    float ap = att_buf[0][t] + att_buf[1][t];
    float a = ap + att_rel[layer*NRELS + rel_s[t]] + att_rq[layer*BB + b] + attb[layer];
    a = (a >= 0.f) ? a : 0.01f*a;
    bool m = em[ge] != 0;
    a = m ? a : MASKV;
    att[ge] = a;
    if (m){
      int tgt = edge_index[(b<<16) + NE + e0 + t];
      atomicMaxF(&mx[(b<<11) + tgt], a);
    }
  }
}

// -------------------------------------------------- softmax pass 2: ex & sum
__global__ void softmax_e_kernel(const int* __restrict__ edge_index,
                                 float* __restrict__ att_ex,
                                 const float* __restrict__ mx,
                                 float* __restrict__ sm)
{
  int gid = blockIdx.x*256 + threadIdx.x;   // B*E threads
  int b = gid >> 15;
  int e = gid & (NE-1);
  int tgt = edge_index[(b<<16) + NE + e];
  float a = att_ex[gid];
  float ex = expf(a - mx[(b<<11) + tgt]);
  att_ex[gid] = ex;
  atomicAdd(&sm[(b<<11) + tgt], ex);
}

// ------------------------------------------- weighted scatter-add of messages
__global__ void aggregate_kernel(const int* __restrict__ edge_index,
                                 const float* __restrict__ att_ex,
                                 const float* __restrict__ sm,
                                 const float* __restrict__ coef,
                                 const ushort_t* __restrict__ raw,
                                 float* __restrict__ aggr)
{
  int gid = blockIdx.x*256 + threadIdx.x;   // B*E*D threads
  int ge = gid >> 7;
  int d = gid & 127;
  float cf = coef[ge];
  if (cf == 0.0f) return;
  int b = ge >> 15;
  int e = ge & (NE-1);
  int tgt = edge_index[(b<<16) + NE + e];
  float alpha = att_ex[ge] / (sm[(b<<11) + tgt] + 1e-8f);
  float w = cf * alpha;
  atomicAdd(&aggr[(size_t)((b<<11) + tgt)*DDIM + d], w * bf2f(raw[(size_t)ge*DDIM + d]));
}

// --------------------------------------------- h = LN(h + aggr@updW + updb)
#define FMA4(acc, a, bv) do { \
    acc.x = fmaf(a, bv.x, acc.x); \
    acc.y = fmaf(a, bv.y, acc.y); \
    acc.z = fmaf(a, bv.z, acc.z); \
    acc.w = fmaf(a, bv.w, acc.w); } while(0)

__global__ __launch_bounds__(256,2) void update_kernel(
    const float* __restrict__ aggr, const float* __restrict__ updW,
    const float* __restrict__ updb,
    const float* __restrict__ lng, const float* __restrict__ lnb,
    float* __restrict__ h, ushort_t* __restrict__ h_bf,
    float* __restrict__ out, int layer)
{
  __shared__ float As[64*65];
  __shared__ float Bs[64*128];
  const int t = threadIdx.x, blk = blockIdx.x;   // 128 blocks
  const int n0 = blk << 6;
  const int c = t & 15, r = t >> 4;
  float4 acc0[4], acc1[4];
  #pragma unroll
  for (int i=0;i<4;++i){ acc0[i]=make_float4(0,0,0,0); acc1[i]=make_float4(0,0,0,0); }
  const float* wbase = updW + (size_t)layer*DDIM*DDIM;

  for (int ch=0; ch<2; ++ch){
    __syncthreads();
    #pragma unroll
    for (int l=0;l<16;++l){
      int idx=(l<<8)+t, ei=idx>>6, kk=idx&63;
      As[ei*65+kk] = aggr[(size_t)(n0+ei)*DDIM + (ch<<6) + kk];
    }
    #pragma unroll
    for (int l=0;l<32;++l){
      int idx=(l<<8)+t, kk=idx>>7, j=idx&127;
      Bs[(kk<<7)+j] = wbase[((ch<<6)+kk)*DDIM + j];
    }
    __syncthreads();
    #pragma unroll 4
    for (int kk=0;kk<64;++kk){
      const float4 b0 = *(const float4*)&Bs[(kk<<7) + (c<<2)];
      const float4 b1 = *(const float4*)&Bs[(kk<<7) + 64 + (c<<2)];
      #pragma unroll
      for (int i=0;i<4;++i){
        const float a = As[((r<<2)+i)*65 + kk];
        FMA4(acc0[i], a, b0);
        FMA4(acc1[i], a, b1);
      }
    }
  }

  const int col0 = c << 2;
  float ub0[4], ub1[4], g0[4], g1[4], lb0[4], lb1[4];
  #pragma unroll
  for (int q=0;q<4;++q){
    ub0[q] = updb[layer*DDIM + col0+q];  ub1[q] = updb[layer*DDIM + 64+col0+q];
    g0[q]  = lng[col0+q];                g1[q]  = lng[64+col0+q];
    lb0[q] = lnb[col0+q];                lb1[q] = lnb[64+col0+q];
  }

  #pragma unroll
  for (int i=0;i<4;++i){
    const int row = n0 + (r<<2) + i;
    float* hrow = h + (size_t)row*DDIM;
    float4 h0 = *(float4*)&hrow[col0];
    float4 h1 = *(float4*)&hrow[64+col0];
    float x0[4], x1[4];
    x0[0] = h0.x + acc0[i].x + ub0[0];
    x0[1] = h0.y + acc0[i].y + ub0[1];
    x0[2] = h0.z + acc0[i].z + ub0[2];
    x0[3] = h0.w + acc0[i].w + ub0[3];
    x1[0] = h1.x + acc1[i].x + ub1[0];
    x1[1] = h1.y + acc1[i].y + ub1[1];
    x1[2] = h1.z + acc1[i].z + ub1[2];
    x1[3] = h1.w + acc1[i].w + ub1[3];
    float s = 0.f, s2 = 0.f;
    #pragma unroll
    for (int q=0;q<4;++q){ s += x0[q]+x1[q]; s2 += x0[q]*x0[q] + x1[q]*x1[q]; }
    #pragma unroll
    for (int off=1; off<16; off<<=1){
      s  += __shfl_xor(s,  off, 16);
      s2 += __shfl_xor(s2, off, 16);
    }
    const float mu = s * (1.0f/128.0f);
    const float var = s2 * (1.0f/128.0f) - mu*mu;
    const float rstd = rsqrtf(var + 1e-5f);
    float4 y0, y1;
    y0.x = (x0[0]-mu)*rstd*g0[0] + lb0[0];
    y0.y = (x0[1]-mu)*rstd*g0[1] + lb0[1];
    y0.z = (x0[2]-mu)*rstd*g0[2] + lb0[2];
    y0.w = (x0[3]-mu)*rstd*g0[3] + lb0[3];
    y1.x = (x1[0]-mu)*rstd*g1[0] + lb1[0];
    y1.y = (x1[1]-mu)*rstd*g1[1] + lb1[1];
    y1.z = (x1[2]-mu)*rstd*g1[2] + lb1[2];
    y1.w = (x1[3]-mu)*rstd*g1[3] + lb1[3];
    *(float4*)&hrow[col0] = y0;
    *(float4*)&hrow[64+col0] = y1;
    ushort4 z0, z1;
    z0.x=f2bf(y0.x); z0.y=f2bf(y0.y); z0.z=f2bf(y0.z); z0.w=f2bf(y0.w);
    z1.x=f2bf(y1.x); z1.y=f2bf(y1.y); z1.z=f2bf(y1.z); z1.w=f2bf(y1.w);
    *(ushort4*)&h_bf[(size_t)row*DDIM + col0] = z0;
    *(ushort4*)&h_bf[(size_t)row*DDIM + 64 + col0] = z1;
    if ((row & (NNODE-1)) == 0){
      const int bb_ = row >> 11;
      float* op = out + (size_t)(bb_*NL + layer)*DDIM;
      *(float4*)&op[col0] = y0;
      *(float4*)&op[64+col0] = y1;
    }
  }
}

// ------------------------------------------------------------------ launcher
extern "C" void kernel_launch(void* const* d_in, const int* in_sizes, int n_in,
                              void* d_out, int out_size, void* d_ws, size_t ws_size,
                              hipStream_t stream) {
  const int*   edge_index = (const int*)d_in[0];
  const int*   rels       = (const int*)d_in[1];
  const float* scores     = (const float*)d_in[2];
  const void*  cm_raw     = d_in[3];
  const void*  em_raw     = d_in[4];
  const float* rq    = (const float*)d_in[6];
  const float* conf  = (const float*)d_in[7];
  const float* relt  = (const float*)d_in[8];
  const float* betaW = (const float*)d_in[9];
  const float* betab = (const float*)d_in[10];
  const float* msgW  = (const float*)d_in[11];
  const float* msgb  = (const float*)d_in[12];
  const float* updW  = (const float*)d_in[13];
  const float* updb  = (const float*)d_in[14];
  const float* lng   = (const float*)d_in[15];
  const float* lnb   = (const float*)d_in[16];
  const float* attW  = (const float*)d_in[17];
  const float* attb  = (const float*)d_in[18];
  const float* denW1 = (const float*)d_in[19];
  const float* denb1 = (const float*)d_in[20];
  const float* denW2 = (const float*)d_in[21];
  const float* denb2 = (const float*)d_in[22];
  float* out = (float*)d_out;
  char* ws = (char*)d_ws;

  size_t off = 0;
  float* h        = (float*)(ws + off); off += (size_t)BB*NNODE*DDIM*4;      //  4 MB
  ushort_t* h_bf  = (ushort_t*)(ws + off); off += (size_t)BB*NNODE*DDIM*2;   //  2 MB
  float* aggr     = (float*)(ws + off); off += (size_t)BB*NNODE*DDIM*4;      //  4 MB
  ushort_t* raw   = (ushort_t*)(ws + off); off += (size_t)BB*NE*DDIM*2;      // 32 MB
  ushort_t* conf_bf = (ushort_t*)(ws + off); off += (size_t)BB*NE*DDIM*2;    // 32 MB
  ushort_t* relt_bf = (ushort_t*)(ws + off); off += (size_t)NRELS*DDIM*2 + 64;
  ushort_t* rq_bf   = (ushort_t*)(ws + off); off += (size_t)BB*DDIM*2 + 64;
  ushort_t* img_msg = (ushort_t*)(ws + off); off += (size_t)30*8192*2;       // 480 KB
  ushort_t* img_den = (ushort_t*)(ws + off); off += (size_t)6*8192*2;        //  96 KB
  float* coef     = (float*)(ws + off); off += (size_t)BB*NE*4;              // 512 KB
  float* att      = (float*)(ws + off); off += (size_t)BB*NE*4;              // 512 KB
  float* mx       = (float*)(ws + off); off += (size_t)BB*NNODE*4;
  float* sm       = (float*)(ws + off); off += (size_t)BB*NNODE*4;
  float* att_rel  = (float*)(ws + off); off += 3*NRELS*4 + 32;
  float* att_rq   = (float*)(ws + off); off += 64;
  float* beta_rel = (float*)(ws + off); off += NRELS*4 + 32;
  float* beta_rq  = (float*)(ws + off); off += 64;
  uint8_t* cm_dec = (uint8_t*)(ws + off); off += (size_t)BB*NE;
  uint8_t* em_dec = (uint8_t*)(ws + off); off += (size_t)BB*NE;
  int* flag       = (int*)(ws + off); off += 64;

  probe_mask_kernel<<<1, 64, 0, stream>>>(cm_raw, flag);
  decode_masks_kernel<<<512, 256, 0, stream>>>(cm_raw, em_raw, flag, cm_dec, em_dec);
  conv_bf16_kernel<<<16384, 256, 0, stream>>>(conf, conf_bf, BB*NE*DDIM/4);
  conv_bf16_kernel<<<125, 256, 0, stream>>>(relt, relt_bf, NRELS*DDIM/4);
  conv_bf16_kernel<<<1, 256, 0, stream>>>(rq, rq_bf, BB*DDIM/4);
  build_wimg_kernel<<<1152, 256, 0, stream>>>(msgW, denW1, img_msg, img_den);
  init_h_kernel<<<4096, 256, 0, stream>>>(h, h_bf);
  precomp_tables_kernel<<<1004, 256, 0, stream>>>(relt, rq, attW, betaW,
                                                  att_rel, att_rq, beta_rel, beta_rq);
  coef_mfma_kernel<<<1024, 256, 0, stream>>>(rels, scores, cm_dec, em_dec,
                                             relt_bf, rq_bf, conf_bf, img_den,
                                             denb1, denW2, denb2,
                                             beta_rel, beta_rq, betab, coef);
  for (int k = 0; k < NL; ++k){
    init_layer_kernel<<<4096, 256, 0, stream>>>(aggr, mx, sm);
    msg_mfma_kernel<<<1024, 256, 0, stream>>>(edge_index, rels, em_dec,
                                              relt_bf, conf_bf, h_bf, img_msg,
                                              msgb, attW, attb, att_rel, att_rq,
                                              raw, att, mx, k);
    softmax_e_kernel<<<512, 256, 0, stream>>>(edge_index, att, mx, sm);
    aggregate_kernel<<<65536, 256, 0, stream>>>(edge_index, att, sm, coef, raw, aggr);
    update_kernel<<<128, 256, 0, stream>>>(aggr, updW, updb, lng, lnb, h, h_bf, out, k);
  }
}